// Round 1
// baseline (460.105 us; speedup 1.0000x reference)
//
#include <hip/hip_runtime.h>

// DynamicPartitionStitch: out[dest[i]] = data[i], dest via rank-within-partition
// lookup into index0/index1. N=1048576, D=64 (16 float4 per row).
//
// Memory-bound: 256MB read + 256MB write + ~12MB metadata => ~85us roofline.
// Every output row is written exactly once (index0+index1 form a permutation),
// so d_out needs no zero-init.

#define BLOCK 256
#define F4_PER_ROW 16  // D=64 floats = 16 float4

// ---- Kernel 1: count zeros per 256-row chunk ----
__global__ void count_zeros_kernel(const int* __restrict__ parts,
                                   int* __restrict__ blockCounts, int n) {
    int i = blockIdx.x * BLOCK + threadIdx.x;
    int is0 = (i < n && parts[i] == 0) ? 1 : 0;
    unsigned long long mask = __ballot(is0);
    __shared__ int wsum[BLOCK / 64];
    int lane = threadIdx.x & 63;
    int wave = threadIdx.x >> 6;
    if (lane == 0) wsum[wave] = __popcll(mask);
    __syncthreads();
    if (threadIdx.x == 0) {
        int s = 0;
        for (int w = 0; w < BLOCK / 64; ++w) s += wsum[w];
        blockCounts[blockIdx.x] = s;
    }
}

// ---- Kernel 2: exclusive scan of block counts (single block, nb <= 4096) ----
__global__ void scan_kernel(const int* __restrict__ blockCounts,
                            int* __restrict__ blockOffsets, int nb) {
    __shared__ int sums[256];
    int t = threadIdx.x;
    int per = (nb + 255) >> 8;  // 16 for N=1M
    if (per > 16) per = 16;     // safety clamp (nb<=4096 by construction)
    int local[16];
    int s = 0;
    for (int j = 0; j < per; ++j) {
        int idx = t * per + j;
        int v = (idx < nb) ? blockCounts[idx] : 0;
        local[j] = s;
        s += v;
    }
    sums[t] = s;
    __syncthreads();
    // Hillis-Steele inclusive scan over 256 thread-sums
    for (int off = 1; off < 256; off <<= 1) {
        int add = (t >= off) ? sums[t - off] : 0;
        __syncthreads();
        sums[t] += add;
        __syncthreads();
    }
    int excl = (t > 0) ? sums[t - 1] : 0;
    for (int j = 0; j < per; ++j) {
        int idx = t * per + j;
        if (idx < nb) blockOffsets[idx] = excl + local[j];
    }
}

// ---- Kernel 3: compute dest per row (ballot prefix + block offset), then
// copy rows: 16 lanes per row, float4 per lane ----
__global__ void scatter_kernel(const float4* __restrict__ data,
                               const int* __restrict__ parts,
                               const int* __restrict__ idx0,
                               const int* __restrict__ idx1,
                               const int* __restrict__ blockZeroOff,
                               float4* __restrict__ out,
                               int n, int n0, int n1) {
    int row0 = blockIdx.x * BLOCK;
    int t = threadIdx.x;
    int i = row0 + t;
    __shared__ int dest[BLOCK];
    __shared__ int wzero[BLOCK / 64];

    int valid = (i < n) ? 1 : 0;
    int is0 = (valid && parts[i] == 0) ? 1 : 0;
    unsigned long long mask = __ballot(is0);
    int lane = t & 63;
    int wave = t >> 6;
    int zerosBeforeInWave = __popcll(mask & ((1ull << lane) - 1ull));
    if (lane == 63) wzero[wave] = zerosBeforeInWave + is0;
    __syncthreads();
    int waveOff = 0;
    for (int w = 0; w < wave; ++w) waveOff += wzero[w];
    int zerosBefore = blockZeroOff[blockIdx.x] + waveOff + zerosBeforeInWave;

    int d = n;  // sentinel: out-of-range -> dropped
    if (valid) {
        if (is0) {
            int r = zerosBefore;
            if (r > n0 - 1) r = n0 - 1;
            d = idx0[r];
        } else {
            int r = i - zerosBefore;  // ones before i
            if (r > n1 - 1) r = n1 - 1;
            d = idx1[r];
        }
    }
    dest[t] = d;
    __syncthreads();

    // Copy phase: group = 16 lanes handles one row (16 float4 = 256B).
    // Waves cover 4 consecutive rows per iteration -> 1KB contiguous reads.
    int g = t >> 4;
    int l = t & 15;
    for (int r = g; r < BLOCK; r += 16) {
        int row = row0 + r;
        if (row >= n) break;
        int dr = dest[r];
        if (dr >= 0 && dr < n)
            out[(size_t)dr * F4_PER_ROW + l] = data[(size_t)row * F4_PER_ROW + l];
    }
}

extern "C" void kernel_launch(void* const* d_in, const int* in_sizes, int n_in,
                              void* d_out, int out_size, void* d_ws, size_t ws_size,
                              hipStream_t stream) {
    const float* data = (const float*)d_in[0];
    const int*   parts = (const int*)d_in[1];
    const int*   idx0 = (const int*)d_in[2];
    const int*   idx1 = (const int*)d_in[3];
    float* out = (float*)d_out;

    int n  = in_sizes[1];  // number of rows (partitions length)
    int n0 = in_sizes[2];
    int n1 = in_sizes[3];

    int nb = (n + BLOCK - 1) / BLOCK;  // 4096 for N=1M

    int* counts  = (int*)d_ws;
    int* offsets = counts + nb;

    count_zeros_kernel<<<nb, BLOCK, 0, stream>>>(parts, counts, n);
    scan_kernel<<<1, 256, 0, stream>>>(counts, offsets, nb);
    scatter_kernel<<<nb, BLOCK, 0, stream>>>((const float4*)data, parts, idx0, idx1,
                                             offsets, (float4*)out, n, n0, n1);
}

// Round 2
// 451.481 us; speedup vs baseline: 1.0191x; 1.0191x over previous
//
#include <hip/hip_runtime.h>

// DynamicPartitionStitch via INVERSE-PERMUTATION GATHER.
//   dest[i] = (parts[i]==0) ? index0[rank0(i)] : index1[rank1(i)]
//   inv[dest[i]] = i            (4B scattered writes, 4MB — L2/MALL absorbs)
//   out[o]      = data[inv[o]]  (coalesced writes, scattered 256B reads)
//
// dest is a permutation of 0..N-1 (n0+n1==N, ranks exact), so inv is fully
// written every launch — no zero-init of out or inv needed.
// Roofline: 256MB read + 256MB write + ~16MB metadata => ~85us at 6.3TB/s.

#define BLOCK 256
#define F4_PER_ROW 16  // D=64 floats = 16 float4

typedef float f4 __attribute__((ext_vector_type(4)));

// ---- Kernel 1: count zeros per 256-row chunk ----
__global__ void count_zeros_kernel(const int* __restrict__ parts,
                                   int* __restrict__ blockCounts, int n) {
    int i = blockIdx.x * BLOCK + threadIdx.x;
    int is0 = (i < n && parts[i] == 0) ? 1 : 0;
    unsigned long long mask = __ballot(is0);
    __shared__ int wsum[BLOCK / 64];
    int lane = threadIdx.x & 63;
    int wave = threadIdx.x >> 6;
    if (lane == 0) wsum[wave] = __popcll(mask);
    __syncthreads();
    if (threadIdx.x == 0) {
        int s = 0;
        for (int w = 0; w < BLOCK / 64; ++w) s += wsum[w];
        blockCounts[blockIdx.x] = s;
    }
}

// ---- Kernel 2: exclusive scan of block counts (single block, nb <= 4096) ----
__global__ void scan_kernel(const int* __restrict__ blockCounts,
                            int* __restrict__ blockOffsets, int nb) {
    __shared__ int sums[256];
    int t = threadIdx.x;
    int per = (nb + 255) >> 8;  // 16 for N=1M
    if (per > 16) per = 16;
    int local[16];
    int s = 0;
    for (int j = 0; j < per; ++j) {
        int idx = t * per + j;
        int v = (idx < nb) ? blockCounts[idx] : 0;
        local[j] = s;
        s += v;
    }
    sums[t] = s;
    __syncthreads();
    for (int off = 1; off < 256; off <<= 1) {
        int add = (t >= off) ? sums[t - off] : 0;
        __syncthreads();
        sums[t] += add;
        __syncthreads();
    }
    int excl = (t > 0) ? sums[t - 1] : 0;
    for (int j = 0; j < per; ++j) {
        int idx = t * per + j;
        if (idx < nb) blockOffsets[idx] = excl + local[j];
    }
}

// ---- Kernel 3: compute dest per row, scatter row index into inv (4B) ----
__global__ void build_inv_kernel(const int* __restrict__ parts,
                                 const int* __restrict__ idx0,
                                 const int* __restrict__ idx1,
                                 const int* __restrict__ blockZeroOff,
                                 int* __restrict__ inv,
                                 int n, int n0, int n1) {
    int i = blockIdx.x * BLOCK + threadIdx.x;
    int t = threadIdx.x;
    __shared__ int wzero[BLOCK / 64];

    int valid = (i < n) ? 1 : 0;
    int is0 = (valid && parts[i] == 0) ? 1 : 0;
    unsigned long long mask = __ballot(is0);
    int lane = t & 63;
    int wave = t >> 6;
    int zerosBeforeInWave = __popcll(mask & ((1ull << lane) - 1ull));
    if (lane == 63) wzero[wave] = zerosBeforeInWave + is0;
    __syncthreads();
    int waveOff = 0;
    for (int w = 0; w < wave; ++w) waveOff += wzero[w];
    int zerosBefore = blockZeroOff[blockIdx.x] + waveOff + zerosBeforeInWave;

    if (valid) {
        int d;
        if (is0) {
            int r = zerosBefore;
            if (r > n0 - 1) r = n0 - 1;
            d = idx0[r];
        } else {
            int r = i - zerosBefore;
            if (r > n1 - 1) r = n1 - 1;
            d = idx1[r];
        }
        if ((unsigned)d < (unsigned)n) inv[d] = i;
    }
}

// ---- Kernel 4: gather — coalesced writes, scattered 256B reads ----
__global__ void gather_kernel(const f4* __restrict__ data,
                              const int* __restrict__ inv,
                              f4* __restrict__ out, int n) {
    size_t total = (size_t)n * F4_PER_ROW;
    size_t stride = (size_t)gridDim.x * blockDim.x;
    size_t g = (size_t)blockIdx.x * blockDim.x + threadIdx.x;
#pragma unroll 4
    for (; g < total; g += stride) {
        int o = (int)(g >> 4);
        int l = (int)(g & 15);
        int s = inv[o];  // 16 lanes share one value -> single broadcast load
        f4 v = __builtin_nontemporal_load(&data[(size_t)s * F4_PER_ROW + l]);
        __builtin_nontemporal_store(v, &out[g]);
    }
}

extern "C" void kernel_launch(void* const* d_in, const int* in_sizes, int n_in,
                              void* d_out, int out_size, void* d_ws, size_t ws_size,
                              hipStream_t stream) {
    const float* data  = (const float*)d_in[0];
    const int*   parts = (const int*)d_in[1];
    const int*   idx0  = (const int*)d_in[2];
    const int*   idx1  = (const int*)d_in[3];
    float* out = (float*)d_out;

    int n  = in_sizes[1];
    int n0 = in_sizes[2];
    int n1 = in_sizes[3];

    int nb = (n + BLOCK - 1) / BLOCK;  // 4096

    int* counts  = (int*)d_ws;       // nb ints
    int* offsets = counts + nb;      // nb ints
    int* inv     = offsets + nb;     // n ints (4MB)

    count_zeros_kernel<<<nb, BLOCK, 0, stream>>>(parts, counts, n);
    scan_kernel<<<1, 256, 0, stream>>>(counts, offsets, nb);
    build_inv_kernel<<<nb, BLOCK, 0, stream>>>(parts, idx0, idx1, offsets, inv, n, n0, n1);

    int gblocks = 4096;  // 1M threads x 16 iters covers N*16 float4
    gather_kernel<<<gblocks, BLOCK, 0, stream>>>((const f4*)data, inv, (f4*)out, n);
}